// Round 5
// baseline (618.343 us; speedup 1.0000x reference)
//
#include <hip/hip_runtime.h>
#include <math.h>

typedef short v8s __attribute__((ext_vector_type(8)));
typedef float v4f __attribute__((ext_vector_type(4)));

#define NVOX 64000      // 40^3
#define NPAD 74088      // 42^3
#define P2   1764       // 42^2
#define GSTR 592704     // NPAD*8
#define NCPY 32         // banked global-accumulator copies
#define ITST (NCPY*260) // stride per kmeans iteration (8320 floats)

__device__ __forceinline__ unsigned short bf16rne(float f){
  unsigned int u = __float_as_uint(f);
  u += 0x7FFFu + ((u >> 16) & 1u);
  return (unsigned short)(u >> 16);
}

__device__ __forceinline__ float cohload(const float* p){
  return __hip_atomic_load(p, __ATOMIC_RELAXED, __HIP_MEMORY_SCOPE_AGENT);
}

// ---------------- projection: xp = proj_w @ x ; fp32 [c][n] and bf16 padded [g][p][8c]
__global__ __launch_bounds__(256) void proj_k(const float* __restrict__ x,
                                              const float* __restrict__ pw,
                                              float* __restrict__ xp,
                                              short* __restrict__ xpt){
  int tid = threadIdx.x;
  int m = (blockIdx.x >> 1) * 256 + tid;
  int half = blockIdx.x & 1;
  float xv[64];
#pragma unroll
  for (int i = 0; i < 64; i++) xv[i] = x[(size_t)i * NVOX + m];
  int d = m / 1600; int r = m - d * 1600; int h = r / 40; int w = r - h * 40;
  int p = ((d + 1) * 42 + (h + 1)) * 42 + (w + 1);
  const float4* pw4 = (const float4*)pw;
  for (int g8 = half * 4; g8 < half * 4 + 4; g8++){
    v8s pk;
#pragma unroll
    for (int j = 0; j < 8; j++){
      int co = g8 * 8 + j;
      float acc = 0.f;
#pragma unroll
      for (int q = 0; q < 16; q++){
        float4 pv = pw4[co * 16 + q];   // wave-uniform -> scalar K$ loads
        acc = fmaf(pv.x, xv[4*q+0], acc);
        acc = fmaf(pv.y, xv[4*q+1], acc);
        acc = fmaf(pv.z, xv[4*q+2], acc);
        acc = fmaf(pv.w, xv[4*q+3], acc);
      }
      xp[(size_t)co * NVOX + m] = acc;
      pk[j] = (short)bf16rne(acc);
    }
    *(v8s*)(xpt + (size_t)g8 * GSTR + (size_t)p * 8) = pk;
  }
}

// ---------------- fused w+h box passes per (c,d) slice (zero pad)
__global__ __launch_bounds__(256) void boxwh_k(const float* __restrict__ in,
                                               float* __restrict__ out){
  __shared__ float s0[1600], s1[1600];
  size_t base = (size_t)blockIdx.x * 1600;
  int t = threadIdx.x;
  for (int e = t; e < 1600; e += 256) s0[e] = in[base + e];
  __syncthreads();
  for (int e = t; e < 1600; e += 256){
    int w = e % 40;
    float s = s0[e];
    if (w > 0)  s += s0[e - 1];
    if (w < 39) s += s0[e + 1];
    s1[e] = s;
  }
  __syncthreads();
  for (int e = t; e < 1600; e += 256){
    int h = e / 40;
    float s = s1[e];
    if (h > 0)  s += s1[e - 40];
    if (h < 39) s += s1[e + 40];
    out[base + e] = s;
  }
}
__global__ void boxd_k(const float* __restrict__ in, float* __restrict__ out){
  int g = blockIdx.x * 256 + threadIdx.x;
  int d = (g / 1600) % 40;
  float s = in[g];
  if (d > 0)  s += in[g - 1600];
  if (d < 39) s += in[g + 1600];
  out[g] = s * (1.f / 27.f);
}

// ---------------- transpose xm [c][n] -> xmt [n][c] (LDS 64x64 tiles)
// block 0 additionally seeds kmeans iter0 bank0: cent0 = first 4 points, cnt=1
// (KM region pre-zeroed by memset).
__global__ __launch_bounds__(256) void transp_k(const float* __restrict__ in,
                                                float* __restrict__ out,
                                                float* __restrict__ km){
  __shared__ float tile[64][65];
  int t = threadIdx.x;
  int nb = blockIdx.x * 64;
  int l = t & 63, g = t >> 6;
  for (int cc = g; cc < 64; cc += 4)
    tile[cc][l] = in[(size_t)cc * NVOX + nb + l];
  __syncthreads();
  if (blockIdx.x == 0){
    km[t] = tile[t & 63][t >> 6];
    if (t < 4) km[256 + t] = 1.f;
  }
  for (int nn = g; nn < 64; nn += 4)
    out[(size_t)(nb + nn) * 64 + l] = tile[l][nn];
}

// ---------------- persistent kmeans: 11 iterations in ONE launch.
// 250 blocks x 256 threads, one point per thread (regs + LDS, loaded once).
// Per iteration: coherent-load banked sums -> centroids -> assign -> LDS
// column-reduce -> device-scope atomicAdd flush to bank (blockIdx&31) ->
// two-level spin barrier (32 group counters -> master). grid.sync measured
// ~35us/sync (R2); launch boundary ~14us (R4); this barrier ~1-2us.
// Co-residency: 250 blocks <= 256 CUs at ~70KB LDS -> guaranteed resident.
__global__ __launch_bounds__(256) void kmeansp_k(const float* __restrict__ xmt,
                                                 float* __restrict__ km,
                                                 int* __restrict__ gcnt,  // [11][32]
                                                 int* __restrict__ gmast, // [11]
                                                 int* __restrict__ idx){
  __shared__ float s_cent[256];
  __shared__ float s_cc[4];
  __shared__ float s_red[260];
  __shared__ float s_x[256 * 65];
  __shared__ int   s_kb[256];
  int t = threadIdx.x, lane = t & 63, wv = t >> 6;
  int n = blockIdx.x * 256 + t;

  // load this thread's point once: registers (dist) + LDS (reduce)
  const float4* xt = (const float4*)(xmt + (size_t)n * 64);
  float4 xq[16];
#pragma unroll
  for (int q = 0; q < 16; q++) xq[q] = xt[q];
#pragma unroll
  for (int q = 0; q < 16; q++){
    s_x[t * 65 + 4*q + 0] = xq[q].x;
    s_x[t * 65 + 4*q + 1] = xq[q].y;
    s_x[t * 65 + 4*q + 2] = xq[q].z;
    s_x[t * 65 + 4*q + 3] = xq[q].w;
  }

  for (int iter = 0; iter <= 10; ++iter){
    const float* kin = km + iter * ITST;
    {
      float sum = 0.f, cnt = 0.f;
#pragma unroll
      for (int s = 0; s < NCPY; s++){
        sum += cohload(&kin[s * 260 + t]);
        cnt += cohload(&kin[s * 260 + 256 + (t >> 6)]);
      }
      s_cent[t] = sum / fmaxf(cnt, 1.f);
    }
    for (int j = t; j < 260; j += 256) s_red[j] = 0.f;
    __syncthreads();
    if (t < 4){
      const float4* cc4 = (const float4*)(s_cent + t * 64);
      float s = 0.f;
#pragma unroll
      for (int q = 0; q < 16; q++){
        float4 v = cc4[q];
        s = fmaf(v.x, v.x, s); s = fmaf(v.y, v.y, s);
        s = fmaf(v.z, v.z, s); s = fmaf(v.w, v.w, s);
      }
      s_cc[t] = s;
    }
    __syncthreads();
    float d0 = 0.f, d1 = 0.f, d2 = 0.f, d3 = 0.f;
    const float4* c4 = (const float4*)s_cent;
#pragma unroll
    for (int q = 0; q < 16; q++){
      float4 p0 = c4[q], p1 = c4[16 + q], p2 = c4[32 + q], p3 = c4[48 + q];
      d0 = fmaf(p0.x, xq[q].x, d0); d0 = fmaf(p0.y, xq[q].y, d0);
      d0 = fmaf(p0.z, xq[q].z, d0); d0 = fmaf(p0.w, xq[q].w, d0);
      d1 = fmaf(p1.x, xq[q].x, d1); d1 = fmaf(p1.y, xq[q].y, d1);
      d1 = fmaf(p1.z, xq[q].z, d1); d1 = fmaf(p1.w, xq[q].w, d1);
      d2 = fmaf(p2.x, xq[q].x, d2); d2 = fmaf(p2.y, xq[q].y, d2);
      d2 = fmaf(p2.z, xq[q].z, d2); d2 = fmaf(p2.w, xq[q].w, d2);
      d3 = fmaf(p3.x, xq[q].x, d3); d3 = fmaf(p3.y, xq[q].y, d3);
      d3 = fmaf(p3.z, xq[q].z, d3); d3 = fmaf(p3.w, xq[q].w, d3);
    }
    float sc0 = s_cc[0] - 2.f * d0;
    float sc1 = s_cc[1] - 2.f * d1;
    float sc2 = s_cc[2] - 2.f * d2;
    float sc3 = s_cc[3] - 2.f * d3;
    int kb = 0; float bs = sc0;
    if (sc1 < bs){ bs = sc1; kb = 1; }
    if (sc2 < bs){ bs = sc2; kb = 2; }
    if (sc3 < bs){ bs = sc3; kb = 3; }
    if (iter == 10){          // uniform across grid: no barrier divergence
      idx[n] = kb;
      return;
    }
    s_kb[t] = kb;
    __syncthreads();
    float a0 = 0.f, a1 = 0.f, a2 = 0.f, a3 = 0.f;
    int rowbase = wv * 64;
#pragma unroll 16
    for (int j = 0; j < 64; j++){
      float v = s_x[(rowbase + j) * 65 + lane];
      int kj = s_kb[rowbase + j];
      a0 += (kj == 0) ? v : 0.f;
      a1 += (kj == 1) ? v : 0.f;
      a2 += (kj == 2) ? v : 0.f;
      a3 += (kj == 3) ? v : 0.f;
    }
    atomicAdd(&s_red[lane], a0);
    atomicAdd(&s_red[64 + lane], a1);
    atomicAdd(&s_red[128 + lane], a2);
    atomicAdd(&s_red[192 + lane], a3);
#pragma unroll
    for (int kk = 0; kk < 4; kk++){
      unsigned long long m = __ballot(kb == kk);
      if (lane == 0) atomicAdd(&s_red[256 + kk], (float)__popcll(m));
    }
    __syncthreads();
    float* kslot = km + (iter + 1) * ITST + (blockIdx.x & 31) * 260;
    for (int j = t; j < 260; j += 256) atomicAdd(&kslot[j], s_red[j]);
    // ---- two-level spin barrier (lane 0 of block only) ----
    __threadfence();           // own atomics globally visible before signal
    __syncthreads();           // all threads of block flushed before t0 signals
    if (t == 0){
      int g = blockIdx.x & 31;
      int gsz = (g < 26) ? 8 : 7;          // 250 = 7*32 + 26
      if (atomicAdd(&gcnt[iter * 32 + g], 1) == gsz - 1)
        atomicAdd(&gmast[iter], 1);
      while (__hip_atomic_load(&gmast[iter], __ATOMIC_ACQUIRE,
                               __HIP_MEMORY_SCOPE_AGENT) < 32)
        __builtin_amdgcn_s_sleep(2);
    }
    __syncthreads();
  }
}

// ---------------- gating MLPs (1 block, 256 thr); sums the 32 banked copies
__global__ void mlp_k(const float* __restrict__ km10,
                      const float* __restrict__ w1, const float* __restrict__ b1,
                      const float* __restrict__ w2, const float* __restrict__ b2,
                      const float* __restrict__ w3, const float* __restrict__ b3,
                      const float* __restrict__ u1, const float* __restrict__ c1,
                      const float* __restrict__ u2, const float* __restrict__ c2,
                      const float* __restrict__ u3, const float* __restrict__ c3,
                      float* __restrict__ wi, float* __restrict__ bias){
  __shared__ float s_feat[256], s_h1[128], s_h2[128], s_g1[64], s_g2[64];
  int t = threadIdx.x;
  {
    float sum = 0.f, cnt = 0.f;
#pragma unroll
    for (int s = 0; s < NCPY; s++){
      sum += km10[s * 260 + t];
      cnt += km10[s * 260 + 256 + (t >> 6)];
    }
    s_feat[t] = sum / fmaxf(cnt, 1.f);
  }
  __syncthreads();
  if (t < 128){
    float z = b1[t];
    for (int i = 0; i < 256; i++) z = fmaf(s_feat[i], w1[i * 128 + t], z);
    s_h1[t] = fmaxf(z, 0.f);
  }
  __syncthreads();
  if (t < 128){
    float z = b2[t];
    for (int i = 0; i < 128; i++) z = fmaf(s_h1[i], w2[i * 128 + t], z);
    s_h2[t] = fmaxf(z, 0.f);
  }
  __syncthreads();
  if (t < 108){
    float z = b3[t];
    for (int i = 0; i < 128; i++) z = fmaf(s_h2[i], w3[i * 108 + t], z);
    wi[t] = 1.f / (1.f + expf(-z));
  }
  if (t < 64){
    float z = c1[t];
    for (int i = 0; i < 256; i++) z = fmaf(s_feat[i], u1[i * 64 + t], z);
    s_g1[t] = fmaxf(z, 0.f);
  }
  __syncthreads();
  if (t < 64){
    float z = c2[t];
    for (int i = 0; i < 64; i++) z = fmaf(s_g1[i], u2[i * 64 + t], z);
    s_g2[t] = fmaxf(z, 0.f);
  }
  __syncthreads();
  {
    float z = c3[t];
    for (int i = 0; i < 64; i++) z = fmaf(s_g2[i], u3[i * 256 + t], z);
    bias[t] = z;
  }
}

// ---------------- base_w fp32 (o,c,t) -> bf16 [t][o][c]
__global__ void bwprep_k(const float* __restrict__ bw, short* __restrict__ bwb){
  int e = blockIdx.x * 256 + threadIdx.x;           // 0 .. 110591
  int t = e >> 12; int rem = e & 4095;
  int o = rem >> 6; int c = rem & 63;
  bwb[e] = (short)bf16rne(bw[(o * 64 + c) * 27 + t]);
}

// ---------------- main dynamic conv
__global__ __launch_bounds__(256) void conv_k(const short* __restrict__ xpt,
                                              const short* __restrict__ bwb,
                                              const float* __restrict__ wi,
                                              const float* __restrict__ bias,
                                              const int* __restrict__ idx,
                                              const float* __restrict__ x,
                                              const float* __restrict__ pa,
                                              float* __restrict__ out){
  static const int POFF[27] = {
    -P2-42-1, -P2-42, -P2-42+1, -P2-1, -P2, -P2+1, -P2+42-1, -P2+42, -P2+42+1,
    -42-1, -42, -42+1, -1, 0, 1, 42-1, 42, 42+1,
    P2-42-1, P2-42, P2-42+1, P2-1, P2, P2+1, P2+42-1, P2+42, P2+42+1 };
  __shared__ float s_wi[108];
  __shared__ float s_bias[256];
  __shared__ float s_acc[64 * 68];
  int tid = threadIdx.x;
  for (int j = tid; j < 108; j += 256) s_wi[j] = wi[j];
  s_bias[tid] = bias[tid];
  __syncthreads();
  int wv = tid >> 6, lane = tid & 63;
  int kc = wv & 1, mh = wv >> 1;
  int col = lane & 15, kg = lane >> 4;
  int vb = blockIdx.x * 64;
  int p4[4], ki4[4];
#pragma unroll
  for (int nt = 0; nt < 4; nt++){
    int v = vb + nt * 16 + col;
    ki4[nt] = idx[v];
    int d = v / 1600; int r = v - d * 1600; int h = r / 40; int w = r - h * 40;
    p4[nt] = ((d + 1) * 42 + (h + 1)) * 42 + (w + 1);
  }
  const short* bg = xpt + (size_t)(kc * 4 + kg) * GSTR;
  const short* bp0 = bg + (size_t)p4[0] * 8;
  const short* bp1 = bg + (size_t)p4[1] * 8;
  const short* bp2 = bg + (size_t)p4[2] * 8;
  const short* bp3 = bg + (size_t)p4[3] * 8;
  int ao0 = (mh * 32 + col) * 64 + kc * 32 + kg * 8;
  int ao1 = ao0 + 16 * 64;
  v4f acc[2][4];
#pragma unroll
  for (int m2 = 0; m2 < 2; m2++)
#pragma unroll
    for (int nt = 0; nt < 4; nt++) acc[m2][nt] = (v4f){0.f, 0.f, 0.f, 0.f};
  v4f zero = {0.f, 0.f, 0.f, 0.f};
#pragma unroll 9
  for (int t = 0; t < 27; t++){
    int po8 = POFF[t] * 8;
    v8s a0 = *(const v8s*)(bwb + t * 4096 + ao0);
    v8s a1 = *(const v8s*)(bwb + t * 4096 + ao1);
    v8s b0 = *(const v8s*)(bp0 + po8);
    v8s b1 = *(const v8s*)(bp1 + po8);
    v8s b2 = *(const v8s*)(bp2 + po8);
    v8s b3 = *(const v8s*)(bp3 + po8);
    float wk0 = s_wi[ki4[0] * 27 + t];
    float wk1 = s_wi[ki4[1] * 27 + t];
    float wk2 = s_wi[ki4[2] * 27 + t];
    float wk3 = s_wi[ki4[3] * 27 + t];
    v4f tp;
    tp = __builtin_amdgcn_mfma_f32_16x16x32_bf16(a0, b0, zero, 0, 0, 0); acc[0][0] += tp * wk0;
    tp = __builtin_amdgcn_mfma_f32_16x16x32_bf16(a1, b0, zero, 0, 0, 0); acc[1][0] += tp * wk0;
    tp = __builtin_amdgcn_mfma_f32_16x16x32_bf16(a0, b1, zero, 0, 0, 0); acc[0][1] += tp * wk1;
    tp = __builtin_amdgcn_mfma_f32_16x16x32_bf16(a1, b1, zero, 0, 0, 0); acc[1][1] += tp * wk1;
    tp = __builtin_amdgcn_mfma_f32_16x16x32_bf16(a0, b2, zero, 0, 0, 0); acc[0][2] += tp * wk2;
    tp = __builtin_amdgcn_mfma_f32_16x16x32_bf16(a1, b2, zero, 0, 0, 0); acc[1][2] += tp * wk2;
    tp = __builtin_amdgcn_mfma_f32_16x16x32_bf16(a0, b3, zero, 0, 0, 0); acc[0][3] += tp * wk3;
    tp = __builtin_amdgcn_mfma_f32_16x16x32_bf16(a1, b3, zero, 0, 0, 0); acc[1][3] += tp * wk3;
  }
  __syncthreads();
  if (kc == 1){
#pragma unroll
    for (int m2 = 0; m2 < 2; m2++)
#pragma unroll
      for (int nt = 0; nt < 4; nt++)
        *(v4f*)(&s_acc[(nt * 16 + col) * 68 + mh * 32 + m2 * 16 + kg * 4]) = acc[m2][nt];
  }
  __syncthreads();
  if (kc == 0){
    float pav = pa[0];
#pragma unroll
    for (int m2 = 0; m2 < 2; m2++){
#pragma unroll
      for (int nt = 0; nt < 4; nt++){
        v4f other = *(const v4f*)(&s_acc[(nt * 16 + col) * 68 + mh * 32 + m2 * 16 + kg * 4]);
        v4f sum = acc[m2][nt] + other;
        int n = vb + nt * 16 + col;
#pragma unroll
        for (int r = 0; r < 4; r++){
          int o = mh * 32 + m2 * 16 + kg * 4 + r;
          float val = sum[r] + s_bias[ki4[nt] * 64 + o];
          val = (val >= 0.f) ? val : pav * val;
          size_t off = (size_t)o * NVOX + n;
          out[off] = val + x[off];
        }
      }
    }
  }
}

extern "C" void kernel_launch(void* const* d_in, const int* in_sizes, int n_in,
                              void* d_out, int out_size, void* d_ws, size_t ws_size,
                              hipStream_t stream){
  const float* x    = (const float*)d_in[0];
  const float* pw   = (const float*)d_in[1];
  const float* bw   = (const float*)d_in[2];
  const float* gkw1 = (const float*)d_in[3];
  const float* gkb1 = (const float*)d_in[4];
  const float* gkw2 = (const float*)d_in[5];
  const float* gkb2 = (const float*)d_in[6];
  const float* gkw3 = (const float*)d_in[7];
  const float* gkb3 = (const float*)d_in[8];
  const float* gbw1 = (const float*)d_in[9];
  const float* gbb1 = (const float*)d_in[10];
  const float* gbw2 = (const float*)d_in[11];
  const float* gbb2 = (const float*)d_in[12];
  const float* gbw3 = (const float*)d_in[13];
  const float* gbb3 = (const float*)d_in[14];
  const float* pa   = (const float*)d_in[15];
  float* outp = (float*)d_out;

  float* ws   = (float*)d_ws;
  float* XP   = ws;                                  // 4,096,000 f ; reused as XMT
  float* BU2  = ws + 4096000;                        // 4,096,000 f
  float* BU1  = ws + 8192000;                        // 4,096,000 f (xm [c][n])
  short* XPT  = (short*)(ws + 12288000);             // 4,741,632 s
  short* BWB  = XPT + (size_t)NPAD * 64;             // 110,592 s
  float* KM   = (float*)(BWB + 110592);              // 11*8320 f
  int*   GC   = (int*)(KM + 11 * ITST);              // 11*32 i (group counters)
  int*   GM   = GC + 11 * 32;                        // 11 i (+pad) master counters
  float* WI   = (float*)(GM + 16);                   // 108 f
  float* BIAS = WI + 108;                            // 256 f
  int*   IDX  = (int*)(BIAS + 256);                  // 64,000 i
  float* XMT  = XP;                                  // xm transposed [n][c]

  hipMemsetAsync(XPT, 0, (size_t)NPAD * 64 * 2, stream);
  hipMemsetAsync(KM, 0, (size_t)(11 * ITST + 368) * 4, stream);
  proj_k<<<500, 256, 0, stream>>>(x, pw, XP, XPT);
  boxwh_k<<<2560, 256, 0, stream>>>(XP, BU2);
  boxd_k<<<16000, 256, 0, stream>>>(BU2, BU1);
  transp_k<<<1000, 256, 0, stream>>>(BU1, XMT, KM);
  kmeansp_k<<<250, 256, 0, stream>>>(XMT, KM, GC, GM, IDX);
  mlp_k<<<1, 256, 0, stream>>>(KM + 10 * ITST,
                               gkw1, gkb1, gkw2, gkb2, gkw3, gkb3,
                               gbw1, gbb1, gbw2, gbb2, gbw3, gbb3,
                               WI, BIAS);
  bwprep_k<<<432, 256, 0, stream>>>(bw, BWB);
  conv_k<<<1000, 256, 0, stream>>>(XPT, BWB, WI, BIAS, IDX, x, pa, outp);
}

// Round 6
// 310.139 us; speedup vs baseline: 1.9938x; 1.9938x over previous
//
#include <hip/hip_runtime.h>
#include <math.h>

typedef short v8s __attribute__((ext_vector_type(8)));
typedef float v4f __attribute__((ext_vector_type(4)));

#define NVOX 64000      // 40^3
#define NPAD 74088      // 42^3
#define P2   1764       // 42^2
#define GSTR 592704     // NPAD*8
#define NCPY 32         // banked global-accumulator copies
#define ITST (NCPY*260) // stride per kmeans iteration (8320 floats)

__device__ __forceinline__ unsigned short bf16rne(float f){
  unsigned int u = __float_as_uint(f);
  u += 0x7FFFu + ((u >> 16) & 1u);
  return (unsigned short)(u >> 16);
}

// ---------------- merged prep: projection (blocks 0..999, 4-way channel split)
// + base_w bf16 repack (blocks 1000..1431) + xpt halo zeroing (blocks 1432..1471).
// All writes disjoint; replaces proj_k + bwprep_k + the 9.5MB XPT memset.
__global__ __launch_bounds__(256) void prep_k(const float* __restrict__ x,
                                              const float* __restrict__ pw,
                                              float* __restrict__ xp,
                                              short* __restrict__ xpt,
                                              const float* __restrict__ bw,
                                              short* __restrict__ bwb){
  int tid = threadIdx.x;
  int bid = blockIdx.x;
  if (bid < 1000){
    // ---- projection: 4 blocks per 256-voxel group, 16 out-channels each
    // (R4 measured proj: occupancy 19% latency-bound at 500 blocks; 1000 blocks
    //  doubles waves/SIMD; redundant x reads absorbed by L2/L3)
    int m = (bid >> 2) * 256 + tid;
    int quarter = bid & 3;
    float xv[64];
#pragma unroll
    for (int i = 0; i < 64; i++) xv[i] = x[(size_t)i * NVOX + m];
    int d = m / 1600; int r = m - d * 1600; int h = r / 40; int w = r - h * 40;
    int p = ((d + 1) * 42 + (h + 1)) * 42 + (w + 1);
    const float4* pw4 = (const float4*)pw;
    for (int g8 = quarter * 2; g8 < quarter * 2 + 2; g8++){
      v8s pk;
#pragma unroll
      for (int j = 0; j < 8; j++){
        int co = g8 * 8 + j;
        float acc = 0.f;
#pragma unroll
        for (int q = 0; q < 16; q++){
          float4 pv = pw4[co * 16 + q];   // wave-uniform -> scalar K$ loads
          acc = fmaf(pv.x, xv[4*q+0], acc);
          acc = fmaf(pv.y, xv[4*q+1], acc);
          acc = fmaf(pv.z, xv[4*q+2], acc);
          acc = fmaf(pv.w, xv[4*q+3], acc);
        }
        xp[(size_t)co * NVOX + m] = acc;
        pk[j] = (short)bf16rne(acc);
      }
      *(v8s*)(xpt + (size_t)g8 * GSTR + (size_t)p * 8) = pk;
    }
  } else if (bid < 1432){
    // ---- base_w fp32 (o,c,t) -> bf16 [t][o][c]
    int e = (bid - 1000) * 256 + tid;               // 0 .. 110591
    int t5 = e >> 12; int rem = e & 4095;
    int o = rem >> 6; int c = rem & 63;
    bwb[e] = (short)bf16rne(bw[(o * 64 + c) * 27 + t5]);
  } else {
    // ---- zero the xpt halo cells (pad shell of the 42^3 volume, 8 groups)
    v8s z = (v8s){0,0,0,0,0,0,0,0};
    for (int p = (bid - 1432) * 256 + tid; p < NPAD; p += 40 * 256){
      int d = p / P2; int rem = p - d * P2; int h = rem / 42; int w = rem - h * 42;
      if (d == 0 || d == 41 || h == 0 || h == 41 || w == 0 || w == 41){
#pragma unroll
        for (int g = 0; g < 8; g++)
          *(v8s*)(xpt + (size_t)g * GSTR + (size_t)p * 8) = z;
      }
    }
  }
}

// ---------------- fused w+h box passes per (c,d) slice (zero pad)
__global__ __launch_bounds__(256) void boxwh_k(const float* __restrict__ in,
                                               float* __restrict__ out){
  __shared__ float s0[1600], s1[1600];
  size_t base = (size_t)blockIdx.x * 1600;
  int t = threadIdx.x;
  for (int e = t; e < 1600; e += 256) s0[e] = in[base + e];
  __syncthreads();
  for (int e = t; e < 1600; e += 256){
    int w = e % 40;
    float s = s0[e];
    if (w > 0)  s += s0[e - 1];
    if (w < 39) s += s0[e + 1];
    s1[e] = s;
  }
  __syncthreads();
  for (int e = t; e < 1600; e += 256){
    int h = e / 40;
    float s = s1[e];
    if (h > 0)  s += s1[e - 40];
    if (h < 39) s += s1[e + 40];
    out[base + e] = s;
  }
}
__global__ void boxd_k(const float* __restrict__ in, float* __restrict__ out){
  int g = blockIdx.x * 256 + threadIdx.x;
  int d = (g / 1600) % 40;
  float s = in[g];
  if (d > 0)  s += in[g - 1600];
  if (d < 39) s += in[g + 1600];
  out[g] = s * (1.f / 27.f);
}

// ---------------- transpose xm [c][n] -> xmt [n][c] (LDS 64x64 tiles)
// + zeroes the KM accumulator region (replaces the KM memset);
// block 0 seeds kmeans iter0 bank0: cent0 = first 4 points, cnt=1.
__global__ __launch_bounds__(256) void transp_k(const float* __restrict__ in,
                                                float* __restrict__ out,
                                                float* __restrict__ km){
  __shared__ float tile[64][65];
  int t = threadIdx.x;
  int nb = blockIdx.x * 64;
  int l = t & 63, g = t >> 6;
  for (int j = 260 + blockIdx.x * 256 + t; j < 11 * ITST; j += 1000 * 256)
    km[j] = 0.f;
  for (int cc = g; cc < 64; cc += 4)
    tile[cc][l] = in[(size_t)cc * NVOX + nb + l];
  __syncthreads();
  if (blockIdx.x == 0){
    km[t] = tile[t & 63][t >> 6];
    if (t < 4) km[256 + t] = 1.f;
  }
  for (int nn = g; nn < 64; nn += 4)
    out[(size_t)(nb + nn) * 64 + l] = tile[l][nn];
}

// ---------------- kmeans assign + reduce (mode 0) or idx write + MLPs (mode 1)
// 250 blocks x 256 threads, one point per thread. kin/kout are NCPY banked
// 260-float copies: centroid load sums all banks (broadcast, L2-hot); the
// partial-sum flush atomicAdds to bank (blockIdx&31) -> chain depth ~8.
// In mode 1, block 0 additionally runs both gating MLPs (s_cent == s_feat),
// replacing the separate mlp_k dispatch.
__global__ __launch_bounds__(256) void assign_k(const float* __restrict__ xmt,
                                                const float* __restrict__ kin,
                                                float* __restrict__ kout,
                                                int* __restrict__ idx, int mode,
                      const float* __restrict__ w1, const float* __restrict__ b1,
                      const float* __restrict__ w2, const float* __restrict__ b2,
                      const float* __restrict__ w3, const float* __restrict__ b3,
                      const float* __restrict__ u1, const float* __restrict__ c1,
                      const float* __restrict__ u2, const float* __restrict__ c2,
                      const float* __restrict__ u3, const float* __restrict__ c3,
                      float* __restrict__ wi, float* __restrict__ bias){
  __shared__ float s_cent[256];
  __shared__ float s_cc[4];
  __shared__ float s_red[260];
  __shared__ float s_x[256 * 65];
  __shared__ int   s_kb[256];
  __shared__ float s_h1[128], s_h2[128], s_g1[64], s_g2[64];
  int t = threadIdx.x, lane = t & 63, wv = t >> 6;
  int n = blockIdx.x * 256 + t;
  {
    float sum = 0.f, cnt = 0.f;
#pragma unroll
    for (int s = 0; s < NCPY; s++){
      sum += kin[s * 260 + t];
      cnt += kin[s * 260 + 256 + (t >> 6)];
    }
    s_cent[t] = sum / fmaxf(cnt, 1.f);
  }
  for (int j = t; j < 260; j += 256) s_red[j] = 0.f;
  __syncthreads();
  if (t < 4){
    const float4* cc4 = (const float4*)(s_cent + t * 64);
    float s = 0.f;
#pragma unroll
    for (int q = 0; q < 16; q++){
      float4 v = cc4[q];
      s = fmaf(v.x, v.x, s); s = fmaf(v.y, v.y, s);
      s = fmaf(v.z, v.z, s); s = fmaf(v.w, v.w, s);
    }
    s_cc[t] = s;
  }
  __syncthreads();
  const float4* xt = (const float4*)(xmt + (size_t)n * 64);
  float4 xq[16];
#pragma unroll
  for (int q = 0; q < 16; q++) xq[q] = xt[q];
  float d0 = 0.f, d1 = 0.f, d2 = 0.f, d3 = 0.f;
  const float4* c4 = (const float4*)s_cent;
#pragma unroll
  for (int q = 0; q < 16; q++){
    float4 p0 = c4[q], p1 = c4[16 + q], p2 = c4[32 + q], p3 = c4[48 + q];
    d0 = fmaf(p0.x, xq[q].x, d0); d0 = fmaf(p0.y, xq[q].y, d0);
    d0 = fmaf(p0.z, xq[q].z, d0); d0 = fmaf(p0.w, xq[q].w, d0);
    d1 = fmaf(p1.x, xq[q].x, d1); d1 = fmaf(p1.y, xq[q].y, d1);
    d1 = fmaf(p1.z, xq[q].z, d1); d1 = fmaf(p1.w, xq[q].w, d1);
    d2 = fmaf(p2.x, xq[q].x, d2); d2 = fmaf(p2.y, xq[q].y, d2);
    d2 = fmaf(p2.z, xq[q].z, d2); d2 = fmaf(p2.w, xq[q].w, d2);
    d3 = fmaf(p3.x, xq[q].x, d3); d3 = fmaf(p3.y, xq[q].y, d3);
    d3 = fmaf(p3.z, xq[q].z, d3); d3 = fmaf(p3.w, xq[q].w, d3);
  }
  float sc0 = s_cc[0] - 2.f * d0;
  float sc1 = s_cc[1] - 2.f * d1;
  float sc2 = s_cc[2] - 2.f * d2;
  float sc3 = s_cc[3] - 2.f * d3;
  int kb = 0; float bs = sc0;
  if (sc1 < bs){ bs = sc1; kb = 1; }
  if (sc2 < bs){ bs = sc2; kb = 2; }
  if (sc3 < bs){ bs = sc3; kb = 3; }
  if (mode){
    idx[n] = kb;
    if (blockIdx.x == 0){
      // gating MLPs; s_cent holds exactly mlp_k's s_feat (same banked sums)
      __syncthreads();
      if (t < 128){
        float z = b1[t];
        for (int i = 0; i < 256; i++) z = fmaf(s_cent[i], w1[i * 128 + t], z);
        s_h1[t] = fmaxf(z, 0.f);
      }
      if (t < 64){
        float z = c1[t];
        for (int i = 0; i < 256; i++) z = fmaf(s_cent[i], u1[i * 64 + t], z);
        s_g1[t] = fmaxf(z, 0.f);
      }
      __syncthreads();
      if (t < 128){
        float z = b2[t];
        for (int i = 0; i < 128; i++) z = fmaf(s_h1[i], w2[i * 128 + t], z);
        s_h2[t] = fmaxf(z, 0.f);
      }
      if (t < 64){
        float z = c2[t];
        for (int i = 0; i < 64; i++) z = fmaf(s_g1[i], u2[i * 64 + t], z);
        s_g2[t] = fmaxf(z, 0.f);
      }
      __syncthreads();
      if (t < 108){
        float z = b3[t];
        for (int i = 0; i < 128; i++) z = fmaf(s_h2[i], w3[i * 108 + t], z);
        wi[t] = 1.f / (1.f + expf(-z));
      }
      {
        float z = c3[t];
        for (int i = 0; i < 64; i++) z = fmaf(s_g2[i], u3[i * 256 + t], z);
        bias[t] = z;
      }
    }
    return;
  }
  s_kb[t] = kb;
#pragma unroll
  for (int q = 0; q < 16; q++){
    s_x[t * 65 + 4*q + 0] = xq[q].x;
    s_x[t * 65 + 4*q + 1] = xq[q].y;
    s_x[t * 65 + 4*q + 2] = xq[q].z;
    s_x[t * 65 + 4*q + 3] = xq[q].w;
  }
  __syncthreads();
  float a0 = 0.f, a1 = 0.f, a2 = 0.f, a3 = 0.f;
  int rowbase = wv * 64;
#pragma unroll 16
  for (int j = 0; j < 64; j++){
    float v = s_x[(rowbase + j) * 65 + lane];
    int kj = s_kb[rowbase + j];
    a0 += (kj == 0) ? v : 0.f;
    a1 += (kj == 1) ? v : 0.f;
    a2 += (kj == 2) ? v : 0.f;
    a3 += (kj == 3) ? v : 0.f;
  }
  atomicAdd(&s_red[lane], a0);
  atomicAdd(&s_red[64 + lane], a1);
  atomicAdd(&s_red[128 + lane], a2);
  atomicAdd(&s_red[192 + lane], a3);
#pragma unroll
  for (int kk = 0; kk < 4; kk++){
    unsigned long long m = __ballot(kb == kk);
    if (lane == 0) atomicAdd(&s_red[256 + kk], (float)__popcll(m));
  }
  __syncthreads();
  float* kslot = kout + (blockIdx.x & (NCPY - 1)) * 260;
  for (int j = t; j < 260; j += 256) atomicAdd(&kslot[j], s_red[j]);
}

// ---------------- main dynamic conv
__global__ __launch_bounds__(256) void conv_k(const short* __restrict__ xpt,
                                              const short* __restrict__ bwb,
                                              const float* __restrict__ wi,
                                              const float* __restrict__ bias,
                                              const int* __restrict__ idx,
                                              const float* __restrict__ x,
                                              const float* __restrict__ pa,
                                              float* __restrict__ out){
  static const int POFF[27] = {
    -P2-42-1, -P2-42, -P2-42+1, -P2-1, -P2, -P2+1, -P2+42-1, -P2+42, -P2+42+1,
    -42-1, -42, -42+1, -1, 0, 1, 42-1, 42, 42+1,
    P2-42-1, P2-42, P2-42+1, P2-1, P2, P2+1, P2+42-1, P2+42, P2+42+1 };
  __shared__ float s_wi[108];
  __shared__ float s_bias[256];
  __shared__ float s_acc[64 * 68];
  int tid = threadIdx.x;
  for (int j = tid; j < 108; j += 256) s_wi[j] = wi[j];
  s_bias[tid] = bias[tid];
  __syncthreads();
  int wv = tid >> 6, lane = tid & 63;
  int kc = wv & 1, mh = wv >> 1;
  int col = lane & 15, kg = lane >> 4;
  int vb = blockIdx.x * 64;
  int p4[4], ki4[4];
#pragma unroll
  for (int nt = 0; nt < 4; nt++){
    int v = vb + nt * 16 + col;
    ki4[nt] = idx[v];
    int d = v / 1600; int r = v - d * 1600; int h = r / 40; int w = r - h * 40;
    p4[nt] = ((d + 1) * 42 + (h + 1)) * 42 + (w + 1);
  }
  const short* bg = xpt + (size_t)(kc * 4 + kg) * GSTR;
  const short* bp0 = bg + (size_t)p4[0] * 8;
  const short* bp1 = bg + (size_t)p4[1] * 8;
  const short* bp2 = bg + (size_t)p4[2] * 8;
  const short* bp3 = bg + (size_t)p4[3] * 8;
  int ao0 = (mh * 32 + col) * 64 + kc * 32 + kg * 8;
  int ao1 = ao0 + 16 * 64;
  v4f acc[2][4];
#pragma unroll
  for (int m2 = 0; m2 < 2; m2++)
#pragma unroll
    for (int nt = 0; nt < 4; nt++) acc[m2][nt] = (v4f){0.f, 0.f, 0.f, 0.f};
  v4f zero = {0.f, 0.f, 0.f, 0.f};
#pragma unroll 9
  for (int t = 0; t < 27; t++){
    int po8 = POFF[t] * 8;
    v8s a0 = *(const v8s*)(bwb + t * 4096 + ao0);
    v8s a1 = *(const v8s*)(bwb + t * 4096 + ao1);
    v8s b0 = *(const v8s*)(bp0 + po8);
    v8s b1 = *(const v8s*)(bp1 + po8);
    v8s b2 = *(const v8s*)(bp2 + po8);
    v8s b3 = *(const v8s*)(bp3 + po8);
    float wk0 = s_wi[ki4[0] * 27 + t];
    float wk1 = s_wi[ki4[1] * 27 + t];
    float wk2 = s_wi[ki4[2] * 27 + t];
    float wk3 = s_wi[ki4[3] * 27 + t];
    v4f tp;
    tp = __builtin_amdgcn_mfma_f32_16x16x32_bf16(a0, b0, zero, 0, 0, 0); acc[0][0] += tp * wk0;
    tp = __builtin_amdgcn_mfma_f32_16x16x32_bf16(a1, b0, zero, 0, 0, 0); acc[1][0] += tp * wk0;
    tp = __builtin_amdgcn_mfma_f32_16x16x32_bf16(a0, b1, zero, 0, 0, 0); acc[0][1] += tp * wk1;
    tp = __builtin_amdgcn_mfma_f32_16x16x32_bf16(a1, b1, zero, 0, 0, 0); acc[1][1] += tp * wk1;
    tp = __builtin_amdgcn_mfma_f32_16x16x32_bf16(a0, b2, zero, 0, 0, 0); acc[0][2] += tp * wk2;
    tp = __builtin_amdgcn_mfma_f32_16x16x32_bf16(a1, b2, zero, 0, 0, 0); acc[1][2] += tp * wk2;
    tp = __builtin_amdgcn_mfma_f32_16x16x32_bf16(a0, b3, zero, 0, 0, 0); acc[0][3] += tp * wk3;
    tp = __builtin_amdgcn_mfma_f32_16x16x32_bf16(a1, b3, zero, 0, 0, 0); acc[1][3] += tp * wk3;
  }
  __syncthreads();
  if (kc == 1){
#pragma unroll
    for (int m2 = 0; m2 < 2; m2++)
#pragma unroll
      for (int nt = 0; nt < 4; nt++)
        *(v4f*)(&s_acc[(nt * 16 + col) * 68 + mh * 32 + m2 * 16 + kg * 4]) = acc[m2][nt];
  }
  __syncthreads();
  if (kc == 0){
    float pav = pa[0];
#pragma unroll
    for (int m2 = 0; m2 < 2; m2++){
#pragma unroll
      for (int nt = 0; nt < 4; nt++){
        v4f other = *(const v4f*)(&s_acc[(nt * 16 + col) * 68 + mh * 32 + m2 * 16 + kg * 4]);
        v4f sum = acc[m2][nt] + other;
        int n = vb + nt * 16 + col;
#pragma unroll
        for (int r = 0; r < 4; r++){
          int o = mh * 32 + m2 * 16 + kg * 4 + r;
          float val = sum[r] + s_bias[ki4[nt] * 64 + o];
          val = (val >= 0.f) ? val : pav * val;
          size_t off = (size_t)o * NVOX + n;
          out[off] = val + x[off];
        }
      }
    }
  }
}

extern "C" void kernel_launch(void* const* d_in, const int* in_sizes, int n_in,
                              void* d_out, int out_size, void* d_ws, size_t ws_size,
                              hipStream_t stream){
  const float* x    = (const float*)d_in[0];
  const float* pw   = (const float*)d_in[1];
  const float* bw   = (const float*)d_in[2];
  const float* gkw1 = (const float*)d_in[3];
  const float* gkb1 = (const float*)d_in[4];
  const float* gkw2 = (const float*)d_in[5];
  const float* gkb2 = (const float*)d_in[6];
  const float* gkw3 = (const float*)d_in[7];
  const float* gkb3 = (const float*)d_in[8];
  const float* gbw1 = (const float*)d_in[9];
  const float* gbb1 = (const float*)d_in[10];
  const float* gbw2 = (const float*)d_in[11];
  const float* gbb2 = (const float*)d_in[12];
  const float* gbw3 = (const float*)d_in[13];
  const float* gbb3 = (const float*)d_in[14];
  const float* pa   = (const float*)d_in[15];
  float* outp = (float*)d_out;

  float* ws   = (float*)d_ws;
  float* XP   = ws;                                  // 4,096,000 f ; reused as XMT
  float* BU2  = ws + 4096000;                        // 4,096,000 f
  float* BU1  = ws + 8192000;                        // 4,096,000 f (xm [c][n])
  short* XPT  = (short*)(ws + 12288000);             // 4,741,632 s
  short* BWB  = XPT + (size_t)NPAD * 64;             // 110,592 s
  float* KM   = (float*)(BWB + 110592);              // 11*8320 f
  float* WI   = KM + 11 * ITST;                      // 108 f
  float* BIAS = WI + 108;                            // 256 f
  int*   IDX  = (int*)(BIAS + 256);                  // 64,000 i
  float* XMT  = XP;                                  // xm transposed [n][c]

  prep_k<<<1472, 256, 0, stream>>>(x, pw, XP, XPT, bw, BWB);
  boxwh_k<<<2560, 256, 0, stream>>>(XP, BU2);
  boxd_k<<<16000, 256, 0, stream>>>(BU2, BU1);
  transp_k<<<1000, 256, 0, stream>>>(BU1, XMT, KM);
  for (int i = 0; i <= 10; i++)
    assign_k<<<250, 256, 0, stream>>>(XMT, KM + i * ITST, KM + (i + 1) * ITST, IDX,
                                      (i == 10) ? 1 : 0,
                                      gkw1, gkb1, gkw2, gkb2, gkw3, gkb3,
                                      gbw1, gbb1, gbw2, gbb2, gbw3, gbb3,
                                      WI, BIAS);
  conv_k<<<1000, 256, 0, stream>>>(XPT, BWB, WI, BIAS, IDX, x, pa, outp);
}